// Round 7
// baseline (466.442 us; speedup 1.0000x reference)
//
#include <hip/hip_runtime.h>

using short8 = __attribute__((ext_vector_type(8))) short;
using f32x4  = __attribute__((ext_vector_type(4))) float;
typedef unsigned short ushort_t;
typedef unsigned int u32;

#define T_TOK 2048
#define DH 2048
#define DE 1408
#define DS 2816
#define NB_GU 800   // >= max live gateup tiles (<=781), multiple of 8
#define NB_DN 880   // >= max live down tiles  (<=880), multiple of 8

__device__ __forceinline__ unsigned short f2bf(float f) {
  unsigned u = __float_as_uint(f);
  u += 0x7FFF + ((u >> 16) & 1);   // round-to-nearest-even
  return (unsigned short)(u >> 16);
}

// async global->LDS 16B; LDS dest must be wave-uniform base (HW adds lane*16).
// Per-lane SOURCE must be monotonic within cachelines (no XOR!) or TCC
// sector-merging fails and write traffic amplifies 4x (R3 post-mortem).
__device__ __forceinline__ void gl_lds16(const void* g, void* l) {
  __builtin_amdgcn_global_load_lds((const __attribute__((address_space(1))) u32*)g,
                                   (__attribute__((address_space(3))) u32*)l, 16, 0, 0);
}

// ---------------- router: softmax -> top2 -> per-expert slot assignment ----------------
__global__ void router_kernel(const float* __restrict__ x, const float* __restrict__ gW,
                              int* __restrict__ counts, int* __restrict__ tok_e,
                              int* __restrict__ tok_slot, float* __restrict__ tok_w) {
  int t = blockIdx.x;
  int lane = threadIdx.x;  // 64 = 1 wave
  float acc[8] = {0.f,0.f,0.f,0.f,0.f,0.f,0.f,0.f};
  const float* xt = x + (size_t)t * DH;
  for (int i = lane; i < DH; i += 64) {
    float xv = xt[i];
#pragma unroll
    for (int e = 0; e < 8; e++) acc[e] += xv * gW[e * DH + i];
  }
#pragma unroll
  for (int e = 0; e < 8; e++) {
#pragma unroll
    for (int off = 32; off > 0; off >>= 1) acc[e] += __shfl_xor(acc[e], off);
  }
  if (lane == 0) {
    float mx = acc[0];
    for (int e = 1; e < 8; e++) mx = fmaxf(mx, acc[e]);
    float p[8], se = 0.f;
    for (int e = 0; e < 8; e++) { p[e] = __expf(acc[e] - mx); se += p[e]; }
    for (int e = 0; e < 8; e++) p[e] /= se;
    int i1 = 0;
    for (int e = 1; e < 8; e++) if (p[e] > p[i1]) i1 = e;
    int i2 = (i1 == 0) ? 1 : 0;
    for (int e = 0; e < 8; e++) if (e != i1 && p[e] > p[i2]) i2 = e;
    int s1 = atomicAdd(&counts[i1], 1);
    int s2 = atomicAdd(&counts[i2], 1);
    tok_e[2 * t] = i1;     tok_e[2 * t + 1] = i2;
    tok_slot[2 * t] = s1;  tok_slot[2 * t + 1] = s2;
    tok_w[2 * t] = p[i1];  tok_w[2 * t + 1] = p[i2];
  }
}

// ---------------- prefix: bases, tile-offset tables, global slot assignment ----------------
__global__ void prefix_assign_kernel(const int* __restrict__ counts, int* __restrict__ ebase,
                                     int* __restrict__ gu_off, int* __restrict__ dn_off,
                                     const int* __restrict__ tok_e, int* __restrict__ tok_slot,
                                     int* __restrict__ slot2tok) {
  __shared__ int sbase[8];
  if (threadIdx.x == 0) {
    int a = 0;
    for (int e = 0; e < 8; e++) { sbase[e] = a; ebase[e] = a; a += counts[e]; }
    int g = 0, d = 0;
    for (int z = 0; z < 8; z++) {
      gu_off[z] = g; dn_off[z] = d;
      int L = (counts[z] + 127) >> 7;
      g += L * 11; d += L * 16;
    }
    gu_off[8] = g; g += 176;   // shared half 0: 16 m-tiles x 11 y
    gu_off[9] = g; g += 176;   // shared half 1
    gu_off[10] = g;
    dn_off[8] = d; d += 256;   // shared down: 16 m x 16 y
    dn_off[9] = d;
  }
  __syncthreads();
  for (int idx = threadIdx.x; idx < T_TOK * 2; idx += blockDim.x) {
    int e = tok_e[idx];
    int g = sbase[e] + tok_slot[idx];
    tok_slot[idx] = g;            // becomes global slot
    slot2tok[g] = idx >> 1;       // token id
  }
}

// ---------------- f32 -> bf16 streaming convert (8 elems/thread) ----------------
__global__ void cvtw_kernel(const float* __restrict__ src, ushort_t* __restrict__ dst) {
  size_t i = ((size_t)blockIdx.x * blockDim.x + threadIdx.x) * 8;
  float4 a = *(const float4*)(src + i);
  float4 b = *(const float4*)(src + i + 4);
  short8 o;
  o[0] = (short)f2bf(a.x); o[1] = (short)f2bf(a.y);
  o[2] = (short)f2bf(a.z); o[3] = (short)f2bf(a.w);
  o[4] = (short)f2bf(b.x); o[5] = (short)f2bf(b.y);
  o[6] = (short)f2bf(b.z); o[7] = (short)f2bf(b.w);
  *(short8*)(dst + i) = o;
}

// ---------------- fused gate+up (bf16 weights), global_load_lds staging ----------------
__global__ __launch_bounds__(256, 2) void gateup_kernel(
    const ushort_t* __restrict__ xb, const int* __restrict__ counts,
    const int* __restrict__ ebase, const int* __restrict__ gu_off,
    const int* __restrict__ slot2tok,
    const ushort_t* __restrict__ Wbg_e, const ushort_t* __restrict__ Wbu_e,
    const ushort_t* __restrict__ Wbg_s, const ushort_t* __restrict__ Wbu_s,
    ushort_t* __restrict__ h_r, ushort_t* __restrict__ h_s) {
  __shared__ char smem[3 * 128 * 64 * 2];   // A | Bg | Bu (16KB each, [128 rows][128B] linear)
  const int AOFF = 0, GOFF = 16384, UOFF = 32768;

  int b = blockIdx.x;
  int c = (b & 7) * (NB_GU >> 3) + (b >> 3);   // bijective XCD chunk
  int off[11];
#pragma unroll
  for (int zz = 0; zz < 11; zz++) off[zz] = gu_off[zz];
  if (c >= off[10]) return;
  int z = 0;
#pragma unroll
  for (int zz = 1; zz < 10; zz++) if (c >= off[zz]) z = zz;
  int cz = c - off[z];

  bool routed = (z < 8);
  int cnt, gbase, Lm;
  const ushort_t *Bg, *Bu;
  if (routed) {
    cnt = counts[z]; gbase = ebase[z];
    Lm = (cnt + 127) >> 7;
    Bg = Wbg_e + (size_t)z * DE * DH;
    Bu = Wbu_e + (size_t)z * DE * DH;
  } else {
    cnt = T_TOK; gbase = 0; Lm = 16;
    Bg = Wbg_s + (size_t)(z - 8) * 1408 * DH;
    Bu = Wbu_s + (size_t)(z - 8) * 1408 * DH;
  }
  int mt = cz % Lm, y = cz / Lm;   // mt fastest: adjacent blocks share the weight panel
  int m0 = mt * 128, n0 = y * 128;

  int tid = threadIdx.x;
  int lane = tid & 63, w = tid >> 6;
  int lr = lane & 15, lk = lane >> 4;
  int wr = w >> 1, wc = w & 1;

  // gl_lds sources: inst (w,j) covers rows (w*4+j)*8 .. +8; this lane handles
  // row r = (w*4+j)*8 + lane/8, 16B chunk lane%8 (monotonic, coalesced)
  const ushort_t* asrc[4];
  const ushort_t* gsrc[4];
  const ushort_t* usrc[4];
#pragma unroll
  for (int j = 0; j < 4; j++) {
    int r = (w * 4 + j) * 8 + (lane >> 3);
    int lrow = m0 + r;
    int tok = routed ? ((lrow < cnt) ? slot2tok[gbase + lrow] : 0) : lrow;
    int ch = (lane & 7) * 8;   // element offset within 64-elem row slice
    asrc[j] = xb + (size_t)tok * DH + ch;
    gsrc[j] = Bg + (size_t)(n0 + r) * DH + ch;
    usrc[j] = Bu + (size_t)(n0 + r) * DH + ch;
  }

  f32x4 accg[4][4] = {};
  f32x4 accu[4][4] = {};

  for (int k0 = 0; k0 < DH; k0 += 64) {
#pragma unroll
    for (int j = 0; j < 4; j++) {
      gl_lds16(asrc[j] + k0, smem + AOFF + (w * 4 + j) * 1024);
      gl_lds16(gsrc[j] + k0, smem + GOFF + (w * 4 + j) * 1024);
      gl_lds16(usrc[j] + k0, smem + UOFF + (w * 4 + j) * 1024);
    }
    __syncthreads();   // compiler drains vmcnt before barrier
#pragma unroll
    for (int ks = 0; ks < 2; ks++) {
      short8 af[4], bg[4], bu[4];
#pragma unroll
      for (int m = 0; m < 4; m++) {
        int rr = wr * 64 + m * 16 + lr;
        af[m] = *(const short8*)(smem + AOFF + rr * 128 + ks * 64 + lk * 16);
      }
#pragma unroll
      for (int n = 0; n < 4; n++) {
        int cc = wc * 64 + n * 16 + lr;
        bg[n] = *(const short8*)(smem + GOFF + cc * 128 + ks * 64 + lk * 16);
        bu[n] = *(const short8*)(smem + UOFF + cc * 128 + ks * 64 + lk * 16);
      }
#pragma unroll
      for (int m = 0; m < 4; m++) {
#pragma unroll
        for (int n = 0; n < 4; n++) {
          accg[m][n] = __builtin_amdgcn_mfma_f32_16x16x32_bf16(af[m], bg[n], accg[m][n], 0, 0, 0);
          accu[m][n] = __builtin_amdgcn_mfma_f32_16x16x32_bf16(af[m], bu[n], accu[m][n], 0, 0, 0);
        }
      }
    }
    __syncthreads();
  }
#pragma unroll
  for (int m = 0; m < 4; m++) {
    int rowl = m0 + wr * 64 + m * 16 + lk * 4;
#pragma unroll
    for (int n = 0; n < 4; n++) {
      int col = n0 + wc * 64 + n * 16 + lr;
#pragma unroll
      for (int j = 0; j < 4; j++) {
        float g = accg[m][n][j], u = accu[m][n][j];
        float s = g / (1.f + __expf(-g));
        unsigned short hv = f2bf(s * u);
        if (routed) {
          if (rowl + j < cnt) h_r[(size_t)(gbase + rowl + j) * DE + col] = hv;
        } else {
          h_s[(size_t)(rowl + j) * DS + (z - 8) * 1408 + col] = hv;
        }
      }
    }
  }
}

// ---------------- down (bf16 weights), global_load_lds staging ----------------
__global__ __launch_bounds__(256, 4) void down_kernel(
    const ushort_t* __restrict__ h_r, const ushort_t* __restrict__ h_s,
    const int* __restrict__ counts, const int* __restrict__ ebase,
    const int* __restrict__ dn_off,
    const ushort_t* __restrict__ Wbd_e, const ushort_t* __restrict__ Wbd_s,
    float* __restrict__ oe, float* __restrict__ out) {
  __shared__ char smem[2 * 128 * 64 * 2];   // A | B
  const int AOFF = 0, BOFF = 16384;

  int b = blockIdx.x;
  int c = (b & 7) * (NB_DN >> 3) + (b >> 3);
  int off[10];
#pragma unroll
  for (int zz = 0; zz < 10; zz++) off[zz] = dn_off[zz];
  if (c >= off[9]) return;
  int z = 0;
#pragma unroll
  for (int zz = 1; zz < 9; zz++) if (c >= off[zz]) z = zz;
  int cz = c - off[z];

  bool routed = (z < 8);
  int cnt, gbase, K, Lm;
  const ushort_t* Abase;
  const ushort_t* B;
  if (routed) {
    cnt = counts[z]; gbase = ebase[z];
    Lm = (cnt + 127) >> 7;
    K = DE;
    Abase = h_r + (size_t)gbase * DE;
    B = Wbd_e + (size_t)z * DH * DE;
  } else {
    cnt = T_TOK; gbase = 0; Lm = 16;
    K = DS;
    Abase = h_s;
    B = Wbd_s;
  }
  int mt = cz % Lm, y = cz / Lm;   // mt fastest: adjacent blocks share the weight panel
  int m0 = mt * 128, n0 = y * 128;

  int tid = threadIdx.x;
  int lane = tid & 63, w = tid >> 6;
  int lr = lane & 15, lk = lane >> 4;
  int wr = w >> 1, wc = w & 1;

  const ushort_t* asrc[4];
  const ushort_t* bsrc[4];
#pragma unroll
  for (int j = 0; j < 4; j++) {
    int r = (w * 4 + j) * 8 + (lane >> 3);
    int ch = (lane & 7) * 8;
    asrc[j] = Abase + (size_t)(m0 + r) * K + ch;
    bsrc[j] = B + (size_t)(n0 + r) * K + ch;
  }

  f32x4 acc[4][4] = {};

  for (int k0 = 0; k0 < K; k0 += 64) {
#pragma unroll
    for (int j = 0; j < 4; j++) {
      gl_lds16(asrc[j] + k0, smem + AOFF + (w * 4 + j) * 1024);
      gl_lds16(bsrc[j] + k0, smem + BOFF + (w * 4 + j) * 1024);
    }
    __syncthreads();
#pragma unroll
    for (int ks = 0; ks < 2; ks++) {
      short8 af[4], bf[4];
#pragma unroll
      for (int m = 0; m < 4; m++) {
        int rr = wr * 64 + m * 16 + lr;
        af[m] = *(const short8*)(smem + AOFF + rr * 128 + ks * 64 + lk * 16);
      }
#pragma unroll
      for (int n = 0; n < 4; n++) {
        int cc = wc * 64 + n * 16 + lr;
        bf[n] = *(const short8*)(smem + BOFF + cc * 128 + ks * 64 + lk * 16);
      }
#pragma unroll
      for (int m = 0; m < 4; m++) {
#pragma unroll
        for (int n = 0; n < 4; n++) {
          acc[m][n] = __builtin_amdgcn_mfma_f32_16x16x32_bf16(af[m], bf[n], acc[m][n], 0, 0, 0);
        }
      }
    }
    __syncthreads();
  }
#pragma unroll
  for (int m = 0; m < 4; m++) {
    int rowl = m0 + wr * 64 + m * 16 + lk * 4;
#pragma unroll
    for (int n = 0; n < 4; n++) {
      int col = n0 + wc * 64 + n * 16 + lr;
#pragma unroll
      for (int j = 0; j < 4; j++) {
        if (routed) {
          if (rowl + j < cnt) oe[(size_t)(gbase + rowl + j) * DH + col] = acc[m][n][j];
        } else {
          out[(size_t)(rowl + j) * DH + col] = acc[m][n][j];
        }
      }
    }
  }
}

// ---------------- combine: out[t] += w1*oe[g1] + w2*oe[g2] ----------------
__global__ void combine_kernel(const int* __restrict__ tok_gslot,
                               const float* __restrict__ tok_w,
                               const float* __restrict__ oe,
                               float* __restrict__ out) {
  int t = blockIdx.x;
  int g1 = tok_gslot[2 * t], g2 = tok_gslot[2 * t + 1];
  float w1 = tok_w[2 * t], w2 = tok_w[2 * t + 1];
  int i = threadIdx.x * 8;
  const float4* p1 = (const float4*)(oe + (size_t)g1 * DH + i);
  const float4* p2 = (const float4*)(oe + (size_t)g2 * DH + i);
  float4* po = (float4*)(out + (size_t)t * DH + i);
  float4 a0 = p1[0], a1 = p1[1];
  float4 b0 = p2[0], b1 = p2[1];
  float4 o0 = po[0], o1 = po[1];
  o0.x += w1 * a0.x + w2 * b0.x;  o0.y += w1 * a0.y + w2 * b0.y;
  o0.z += w1 * a0.z + w2 * b0.z;  o0.w += w1 * a0.w + w2 * b0.w;
  o1.x += w1 * a1.x + w2 * b1.x;  o1.y += w1 * a1.y + w2 * b1.y;
  o1.z += w1 * a1.z + w2 * b1.z;  o1.w += w1 * a1.w + w2 * b1.w;
  po[0] = o0; po[1] = o1;
}

extern "C" void kernel_launch(void* const* d_in, const int* in_sizes, int n_in,
                              void* d_out, int out_size, void* d_ws, size_t ws_size,
                              hipStream_t stream) {
  const float* x    = (const float*)d_in[0];
  const float* gW   = (const float*)d_in[1];
  const float* Wg_e = (const float*)d_in[2];
  const float* Wu_e = (const float*)d_in[3];
  const float* Wd_e = (const float*)d_in[4];
  const float* Wg_s = (const float*)d_in[5];
  const float* Wu_s = (const float*)d_in[6];
  const float* Wd_s = (const float*)d_in[7];
  float* out = (float*)d_out;

  char* ws = (char*)d_ws;
  int*   counts   = (int*)ws;                       // 8 ints
  int*   ebase    = (int*)(ws + 64);                // 8 ints
  int*   gu_off   = (int*)(ws + 128);               // 11 ints
  int*   dn_off   = (int*)(ws + 192);               // 10 ints
  int*   tok_e    = (int*)(ws + 256);               // 16KB
  int*   tok_slot = (int*)(ws + 256 + 16384);       // 16KB (-> global slots)
  float* tok_w    = (float*)(ws + 256 + 32768);     // 16KB
  int*   slot2tok = (int*)(ws + 256 + 49152);       // 16KB
  ushort_t* xb  = (ushort_t*)(ws + 131072);                              // 8MB
  ushort_t* h_r = (ushort_t*)(ws + 131072 + (size_t)T_TOK * DH * 2);     // 11.53MB
  ushort_t* h_s = h_r + (size_t)4096 * DE;                               // 11.53MB
  float*    oe  = (float*)((char*)h_s + (size_t)T_TOK * DS * 2);         // 32MB
  // bf16 weights: 86.5M elements = 173MB
  ushort_t* wb  = (ushort_t*)((char*)oe + (size_t)4096 * DH * 4);
  const size_t NGE = (size_t)8 * DE * DH;   // 23,068,672
  const size_t NGS = (size_t)DS * DH;       // 5,767,168
  ushort_t* wbg_e = wb;
  ushort_t* wbu_e = wb + NGE;
  ushort_t* wbd_e = wb + 2 * NGE;
  ushort_t* wbg_s = wb + 3 * NGE;
  ushort_t* wbu_s = wbg_s + NGS;
  ushort_t* wbd_s = wbg_s + 2 * NGS;

  hipMemsetAsync(counts, 0, 64, stream);
  router_kernel<<<T_TOK, 64, 0, stream>>>(x, gW, counts, tok_e, tok_slot, tok_w);
  prefix_assign_kernel<<<1, 256, 0, stream>>>(counts, ebase, gu_off, dn_off,
                                              tok_e, tok_slot, slot2tok);
  // weight + activation bf16 conversion
  cvtw_kernel<<<(T_TOK * DH) / 2048, 256, 0, stream>>>(x, xb);
  cvtw_kernel<<<NGE / 2048, 256, 0, stream>>>(Wg_e, wbg_e);
  cvtw_kernel<<<NGE / 2048, 256, 0, stream>>>(Wu_e, wbu_e);
  cvtw_kernel<<<NGE / 2048, 256, 0, stream>>>(Wd_e, wbd_e);
  cvtw_kernel<<<NGS / 2048, 256, 0, stream>>>(Wg_s, wbg_s);
  cvtw_kernel<<<NGS / 2048, 256, 0, stream>>>(Wu_s, wbu_s);
  cvtw_kernel<<<NGS / 2048, 256, 0, stream>>>(Wd_s, wbd_s);

  gateup_kernel<<<NB_GU, 256, 0, stream>>>(
      xb, counts, ebase, gu_off, slot2tok, wbg_e, wbu_e, wbg_s, wbu_s, h_r, h_s);
  down_kernel<<<NB_DN, 256, 0, stream>>>(
      h_r, h_s, counts, ebase, dn_off, wbd_e, wbd_s, oe, out);
  combine_kernel<<<T_TOK, 256, 0, stream>>>(tok_slot, tok_w, oe, out);
}

// Round 8
// 431.609 us; speedup vs baseline: 1.0807x; 1.0807x over previous
//
#include <hip/hip_runtime.h>

using short8 = __attribute__((ext_vector_type(8))) short;
using f32x4  = __attribute__((ext_vector_type(4))) float;
typedef unsigned short ushort_t;
typedef unsigned int u32;

#define T_TOK 2048
#define DH 2048
#define DE 1408
#define DS 2816
#define NB_GU 800   // >= max live gateup tiles (<=781), multiple of 8
#define NB_DN 880   // >= max live down tiles  (<=880), multiple of 8

__device__ __forceinline__ unsigned short f2bf(float f) {
  unsigned u = __float_as_uint(f);
  u += 0x7FFF + ((u >> 16) & 1);   // round-to-nearest-even
  return (unsigned short)(u >> 16);
}

// async global->LDS 16B; LDS dest = wave-uniform base + lane*16 (linear).
__device__ __forceinline__ void gl_lds16(const void* g, void* l) {
  __builtin_amdgcn_global_load_lds((const __attribute__((address_space(1))) u32*)g,
                                   (__attribute__((address_space(3))) u32*)l, 16, 0, 0);
}

// ---------------- router ----------------
__global__ void router_kernel(const float* __restrict__ x, const float* __restrict__ gW,
                              int* __restrict__ counts, int* __restrict__ tok_e,
                              int* __restrict__ tok_slot, float* __restrict__ tok_w) {
  int t = blockIdx.x;
  int lane = threadIdx.x;  // 64 = 1 wave
  float acc[8] = {0.f,0.f,0.f,0.f,0.f,0.f,0.f,0.f};
  const float* xt = x + (size_t)t * DH;
  for (int i = lane; i < DH; i += 64) {
    float xv = xt[i];
#pragma unroll
    for (int e = 0; e < 8; e++) acc[e] += xv * gW[e * DH + i];
  }
#pragma unroll
  for (int e = 0; e < 8; e++) {
#pragma unroll
    for (int off = 32; off > 0; off >>= 1) acc[e] += __shfl_xor(acc[e], off);
  }
  if (lane == 0) {
    float mx = acc[0];
    for (int e = 1; e < 8; e++) mx = fmaxf(mx, acc[e]);
    float p[8], se = 0.f;
    for (int e = 0; e < 8; e++) { p[e] = __expf(acc[e] - mx); se += p[e]; }
    for (int e = 0; e < 8; e++) p[e] /= se;
    int i1 = 0;
    for (int e = 1; e < 8; e++) if (p[e] > p[i1]) i1 = e;
    int i2 = (i1 == 0) ? 1 : 0;
    for (int e = 0; e < 8; e++) if (e != i1 && p[e] > p[i2]) i2 = e;
    int s1 = atomicAdd(&counts[i1], 1);
    int s2 = atomicAdd(&counts[i2], 1);
    tok_e[2 * t] = i1;     tok_e[2 * t + 1] = i2;
    tok_slot[2 * t] = s1;  tok_slot[2 * t + 1] = s2;
    tok_w[2 * t] = p[i1];  tok_w[2 * t + 1] = p[i2];
  }
}

// ---------------- prefix ----------------
__global__ void prefix_assign_kernel(const int* __restrict__ counts, int* __restrict__ ebase,
                                     int* __restrict__ gu_off, int* __restrict__ dn_off,
                                     const int* __restrict__ tok_e, int* __restrict__ tok_slot,
                                     int* __restrict__ slot2tok) {
  __shared__ int sbase[8];
  if (threadIdx.x == 0) {
    int a = 0;
    for (int e = 0; e < 8; e++) { sbase[e] = a; ebase[e] = a; a += counts[e]; }
    int g = 0, d = 0;
    for (int z = 0; z < 8; z++) {
      gu_off[z] = g; dn_off[z] = d;
      int L = (counts[z] + 127) >> 7;
      g += L * 11; d += L * 16;
    }
    gu_off[8] = g; g += 176;
    gu_off[9] = g; g += 176;
    gu_off[10] = g;
    dn_off[8] = d; d += 256;
    dn_off[9] = d;
  }
  __syncthreads();
  for (int idx = threadIdx.x; idx < T_TOK * 2; idx += blockDim.x) {
    int e = tok_e[idx];
    int g = sbase[e] + tok_slot[idx];
    tok_slot[idx] = g;
    slot2tok[g] = idx >> 1;
  }
}

// ---------------- f32 -> bf16 streaming convert ----------------
__global__ void cvtw_kernel(const float* __restrict__ src, ushort_t* __restrict__ dst) {
  size_t i = ((size_t)blockIdx.x * blockDim.x + threadIdx.x) * 8;
  float4 a = *(const float4*)(src + i);
  float4 b = *(const float4*)(src + i + 4);
  short8 o;
  o[0] = (short)f2bf(a.x); o[1] = (short)f2bf(a.y);
  o[2] = (short)f2bf(a.z); o[3] = (short)f2bf(a.w);
  o[4] = (short)f2bf(b.x); o[5] = (short)f2bf(b.y);
  o[6] = (short)f2bf(b.z); o[7] = (short)f2bf(b.w);
  *(short8*)(dst + i) = o;
}

// ---------------- gateup: BK=32, 2-phase dbuf, gl_lds linear ----------------
#define GU_BK 32
#define GU_BUF 24576   // 3 operands x 8KB
__global__ __launch_bounds__(256, 2) void gateup_kernel(
    const ushort_t* __restrict__ xb, const int* __restrict__ counts,
    const int* __restrict__ ebase, const int* __restrict__ gu_off,
    const int* __restrict__ slot2tok,
    const ushort_t* __restrict__ Wbg_e, const ushort_t* __restrict__ Wbu_e,
    const ushort_t* __restrict__ Wbg_s, const ushort_t* __restrict__ Wbu_s,
    ushort_t* __restrict__ h_r, ushort_t* __restrict__ h_s) {
  __shared__ char smem[2 * GU_BUF];   // dbuf{ A | Bg | Bu } 8KB each, rows of 64B linear
  const int AOFF = 0, GOFF = 8192, UOFF = 16384;

  int b = blockIdx.x;
  int c = (b & 7) * (NB_GU >> 3) + (b >> 3);
  int off[11];
#pragma unroll
  for (int zz = 0; zz < 11; zz++) off[zz] = gu_off[zz];
  if (c >= off[10]) return;
  int z = 0;
#pragma unroll
  for (int zz = 1; zz < 10; zz++) if (c >= off[zz]) z = zz;
  int cz = c - off[z];

  bool routed = (z < 8);
  int cnt, gbase, Lm;
  const ushort_t *Bg, *Bu;
  if (routed) {
    cnt = counts[z]; gbase = ebase[z];
    Lm = (cnt + 127) >> 7;
    Bg = Wbg_e + (size_t)z * DE * DH;
    Bu = Wbu_e + (size_t)z * DE * DH;
  } else {
    cnt = T_TOK; gbase = 0; Lm = 16;
    Bg = Wbg_s + (size_t)(z - 8) * 1408 * DH;
    Bu = Wbu_s + (size_t)(z - 8) * 1408 * DH;
  }
  int mt = cz % Lm, y = cz / Lm;
  int m0 = mt * 128, n0 = y * 128;

  int tid = threadIdx.x;
  int lane = tid & 63, w = tid >> 6;
  int lr = lane & 15, lk = lane >> 4;
  int wr = w >> 1, wc = w & 1;

  // staging: inst i = w*2+j covers rows i*16..+16; lane handles row i*16+lane/4,
  // 16B chunk lane%4 of the 64B (32-elem) row slice. Monotonic per-lane source.
  const ushort_t* asrc[2];
  const ushort_t* gsrc[2];
  const ushort_t* usrc[2];
#pragma unroll
  for (int j = 0; j < 2; j++) {
    int r = (w * 2 + j) * 16 + (lane >> 2);
    int lrow = m0 + r;
    int tok = routed ? ((lrow < cnt) ? slot2tok[gbase + lrow] : 0) : lrow;
    int ch = (lane & 3) * 8;   // element offset within 32-elem slice
    asrc[j] = xb + (size_t)tok * DH + ch;
    gsrc[j] = Bg + (size_t)(n0 + r) * DH + ch;
    usrc[j] = Bu + (size_t)(n0 + r) * DH + ch;
  }

  f32x4 accg[4][4] = {};
  f32x4 accu[4][4] = {};

#define GU_STAGE(buf, k0)                                             \
  {                                                                   \
    char* bb = smem + (buf) * GU_BUF;                                 \
    _Pragma("unroll")                                                 \
    for (int j = 0; j < 2; j++) {                                     \
      gl_lds16(asrc[j] + (k0), bb + AOFF + (w * 2 + j) * 1024);       \
      gl_lds16(gsrc[j] + (k0), bb + GOFF + (w * 2 + j) * 1024);       \
      gl_lds16(usrc[j] + (k0), bb + UOFF + (w * 2 + j) * 1024);       \
    }                                                                 \
  }

  GU_STAGE(0, 0);
  __syncthreads();
  int cur = 0;
  for (int k0 = 0; k0 < DH; k0 += GU_BK) {
    if (k0 + GU_BK < DH) GU_STAGE(cur ^ 1, k0 + GU_BK);
    const char* bb = smem + cur * GU_BUF;
    short8 af[4], bg[4], bu[4];
#pragma unroll
    for (int m = 0; m < 4; m++) {
      int rr = wr * 64 + m * 16 + lr;
      af[m] = *(const short8*)(bb + AOFF + rr * 64 + lk * 16);
    }
#pragma unroll
    for (int n = 0; n < 4; n++) {
      int cc = wc * 64 + n * 16 + lr;
      bg[n] = *(const short8*)(bb + GOFF + cc * 64 + lk * 16);
      bu[n] = *(const short8*)(bb + UOFF + cc * 64 + lk * 16);
    }
#pragma unroll
    for (int m = 0; m < 4; m++) {
#pragma unroll
      for (int n = 0; n < 4; n++) {
        accg[m][n] = __builtin_amdgcn_mfma_f32_16x16x32_bf16(af[m], bg[n], accg[m][n], 0, 0, 0);
        accu[m][n] = __builtin_amdgcn_mfma_f32_16x16x32_bf16(af[m], bu[n], accu[m][n], 0, 0, 0);
      }
    }
    __syncthreads();   // drains vmcnt(0): prefetch had the whole MFMA phase in flight
    cur ^= 1;
  }
#pragma unroll
  for (int m = 0; m < 4; m++) {
    int rowl = m0 + wr * 64 + m * 16 + lk * 4;
#pragma unroll
    for (int n = 0; n < 4; n++) {
      int col = n0 + wc * 64 + n * 16 + lr;
#pragma unroll
      for (int j = 0; j < 4; j++) {
        float g = accg[m][n][j], u = accu[m][n][j];
        float s = g / (1.f + __expf(-g));
        unsigned short hv = f2bf(s * u);
        if (routed) {
          if (rowl + j < cnt) h_r[(size_t)(gbase + rowl + j) * DE + col] = hv;
        } else {
          h_s[(size_t)(rowl + j) * DS + (z - 8) * 1408 + col] = hv;
        }
      }
    }
  }
}

// ---------------- down: BK=64, 2-phase dbuf, gl_lds + BOTH-SIDES swizzle (A/B test) ----------------
#define DN_BUF 32768   // 2 operands x 16KB
__global__ __launch_bounds__(256, 2) void down_kernel(
    const ushort_t* __restrict__ h_r, const ushort_t* __restrict__ h_s,
    const int* __restrict__ counts, const int* __restrict__ ebase,
    const int* __restrict__ dn_off,
    const ushort_t* __restrict__ Wbd_e, const ushort_t* __restrict__ Wbd_s,
    float* __restrict__ oe, float* __restrict__ out) {
  __shared__ char smem[2 * DN_BUF];   // dbuf{ A | B } 16KB each, rows of 128B linear
  const int AOFF = 0, BOFF = 16384;

  int b = blockIdx.x;
  int c = (b & 7) * (NB_DN >> 3) + (b >> 3);
  int off[10];
#pragma unroll
  for (int zz = 0; zz < 10; zz++) off[zz] = dn_off[zz];
  if (c >= off[9]) return;
  int z = 0;
#pragma unroll
  for (int zz = 1; zz < 9; zz++) if (c >= off[zz]) z = zz;
  int cz = c - off[z];

  bool routed = (z < 8);
  int cnt, gbase, K, Lm;
  const ushort_t* Abase;
  const ushort_t* B;
  if (routed) {
    cnt = counts[z]; gbase = ebase[z];
    Lm = (cnt + 127) >> 7;
    K = DE;
    Abase = h_r + (size_t)gbase * DE;
    B = Wbd_e + (size_t)z * DH * DE;
  } else {
    cnt = T_TOK; gbase = 0; Lm = 16;
    K = DS;
    Abase = h_s;
    B = Wbd_s;
  }
  int mt = cz % Lm, y = cz / Lm;
  int m0 = mt * 128, n0 = y * 128;

  int tid = threadIdx.x;
  int lane = tid & 63, w = tid >> 6;
  int lr = lane & 15, lk = lane >> 4;
  int wr = w >> 1, wc = w & 1;

  // staging: inst i = w*4+j covers rows i*8..+8; lane -> row i*8+lane/8,
  // chunk c = lane%8 PRE-SWIZZLED: source chunk = c ^ (r&7). LDS slot (r,c)
  // then holds global chunk c^(r&7); read applies the same XOR (rule 21 pair).
  const ushort_t* asrc[4];
  const ushort_t* bsrc[4];
#pragma unroll
  for (int j = 0; j < 4; j++) {
    int r = (w * 4 + j) * 8 + (lane >> 3);
    int ch = ((lane & 7) ^ (r & 7)) * 8;
    asrc[j] = Abase + (size_t)(m0 + r) * K + ch;
    bsrc[j] = B + (size_t)(n0 + r) * K + ch;
  }

  f32x4 acc[4][4] = {};

#define DN_STAGE(buf, k0)                                             \
  {                                                                   \
    char* bb = smem + (buf) * DN_BUF;                                 \
    _Pragma("unroll")                                                 \
    for (int j = 0; j < 4; j++) {                                     \
      gl_lds16(asrc[j] + (k0), bb + AOFF + (w * 4 + j) * 1024);       \
      gl_lds16(bsrc[j] + (k0), bb + BOFF + (w * 4 + j) * 1024);       \
    }                                                                 \
  }

  DN_STAGE(0, 0);
  __syncthreads();
  int cur = 0;
  for (int k0 = 0; k0 < K; k0 += 64) {
    if (k0 + 64 < K) DN_STAGE(cur ^ 1, k0 + 64);
    const char* bb = smem + cur * DN_BUF;
#pragma unroll
    for (int ks = 0; ks < 2; ks++) {
      short8 af[4], bf[4];
#pragma unroll
      for (int m = 0; m < 4; m++) {
        int rr = wr * 64 + m * 16 + lr;
        af[m] = *(const short8*)(bb + AOFF + rr * 128 + ((ks * 64 + lk * 16) ^ ((rr & 7) << 4)));
      }
#pragma unroll
      for (int n = 0; n < 4; n++) {
        int cc = wc * 64 + n * 16 + lr;
        bf[n] = *(const short8*)(bb + BOFF + cc * 128 + ((ks * 64 + lk * 16) ^ ((cc & 7) << 4)));
      }
#pragma unroll
      for (int m = 0; m < 4; m++) {
#pragma unroll
        for (int n = 0; n < 4; n++) {
          acc[m][n] = __builtin_amdgcn_mfma_f32_16x16x32_bf16(af[m], bf[n], acc[m][n], 0, 0, 0);
        }
      }
    }
    __syncthreads();
    cur ^= 1;
  }
#pragma unroll
  for (int m = 0; m < 4; m++) {
    int rowl = m0 + wr * 64 + m * 16 + lk * 4;
#pragma unroll
    for (int n = 0; n < 4; n++) {
      int col = n0 + wc * 64 + n * 16 + lr;
#pragma unroll
      for (int j = 0; j < 4; j++) {
        if (routed) {
          if (rowl + j < cnt) oe[(size_t)(gbase + rowl + j) * DH + col] = acc[m][n][j];
        } else {
          out[(size_t)(rowl + j) * DH + col] = acc[m][n][j];
        }
      }
    }
  }
}

// ---------------- combine ----------------
__global__ void combine_kernel(const int* __restrict__ tok_gslot,
                               const float* __restrict__ tok_w,
                               const float* __restrict__ oe,
                               float* __restrict__ out) {
  int t = blockIdx.x;
  int g1 = tok_gslot[2 * t], g2 = tok_gslot[2 * t + 1];
  float w1 = tok_w[2 * t], w2 = tok_w[2 * t + 1];
  int i = threadIdx.x * 8;
  const float4* p1 = (const float4*)(oe + (size_t)g1 * DH + i);
  const float4* p2 = (const float4*)(oe + (size_t)g2 * DH + i);
  float4* po = (float4*)(out + (size_t)t * DH + i);
  float4 a0 = p1[0], a1 = p1[1];
  float4 b0 = p2[0], b1 = p2[1];
  float4 o0 = po[0], o1 = po[1];
  o0.x += w1 * a0.x + w2 * b0.x;  o0.y += w1 * a0.y + w2 * b0.y;
  o0.z += w1 * a0.z + w2 * b0.z;  o0.w += w1 * a0.w + w2 * b0.w;
  o1.x += w1 * a1.x + w2 * b1.x;  o1.y += w1 * a1.y + w2 * b1.y;
  o1.z += w1 * a1.z + w2 * b1.z;  o1.w += w1 * a1.w + w2 * b1.w;
  po[0] = o0; po[1] = o1;
}

extern "C" void kernel_launch(void* const* d_in, const int* in_sizes, int n_in,
                              void* d_out, int out_size, void* d_ws, size_t ws_size,
                              hipStream_t stream) {
  const float* x    = (const float*)d_in[0];
  const float* gW   = (const float*)d_in[1];
  const float* Wg_e = (const float*)d_in[2];
  const float* Wu_e = (const float*)d_in[3];
  const float* Wd_e = (const float*)d_in[4];
  const float* Wg_s = (const float*)d_in[5];
  const float* Wu_s = (const float*)d_in[6];
  const float* Wd_s = (const float*)d_in[7];
  float* out = (float*)d_out;

  char* ws = (char*)d_ws;
  int*   counts   = (int*)ws;
  int*   ebase    = (int*)(ws + 64);
  int*   gu_off   = (int*)(ws + 128);
  int*   dn_off   = (int*)(ws + 192);
  int*   tok_e    = (int*)(ws + 256);
  int*   tok_slot = (int*)(ws + 256 + 16384);
  float* tok_w    = (float*)(ws + 256 + 32768);
  int*   slot2tok = (int*)(ws + 256 + 49152);
  ushort_t* xb  = (ushort_t*)(ws + 131072);
  ushort_t* h_r = (ushort_t*)(ws + 131072 + (size_t)T_TOK * DH * 2);
  ushort_t* h_s = h_r + (size_t)4096 * DE;
  float*    oe  = (float*)((char*)h_s + (size_t)T_TOK * DS * 2);
  ushort_t* wb  = (ushort_t*)((char*)oe + (size_t)4096 * DH * 4);
  const size_t NGE = (size_t)8 * DE * DH;
  const size_t NGS = (size_t)DS * DH;
  ushort_t* wbg_e = wb;
  ushort_t* wbu_e = wb + NGE;
  ushort_t* wbd_e = wb + 2 * NGE;
  ushort_t* wbg_s = wb + 3 * NGE;
  ushort_t* wbu_s = wbg_s + NGS;
  ushort_t* wbd_s = wbg_s + 2 * NGS;

  hipMemsetAsync(counts, 0, 64, stream);
  router_kernel<<<T_TOK, 64, 0, stream>>>(x, gW, counts, tok_e, tok_slot, tok_w);
  prefix_assign_kernel<<<1, 256, 0, stream>>>(counts, ebase, gu_off, dn_off,
                                              tok_e, tok_slot, slot2tok);
  cvtw_kernel<<<(T_TOK * DH) / 2048, 256, 0, stream>>>(x, xb);
  cvtw_kernel<<<NGE / 2048, 256, 0, stream>>>(Wg_e, wbg_e);
  cvtw_kernel<<<NGE / 2048, 256, 0, stream>>>(Wu_e, wbu_e);
  cvtw_kernel<<<NGE / 2048, 256, 0, stream>>>(Wd_e, wbd_e);
  cvtw_kernel<<<NGS / 2048, 256, 0, stream>>>(Wg_s, wbg_s);
  cvtw_kernel<<<NGS / 2048, 256, 0, stream>>>(Wu_s, wbu_s);
  cvtw_kernel<<<NGS / 2048, 256, 0, stream>>>(Wd_s, wbd_s);

  gateup_kernel<<<NB_GU, 256, 0, stream>>>(
      xb, counts, ebase, gu_off, slot2tok, wbg_e, wbu_e, wbg_s, wbu_s, h_r, h_s);
  down_kernel<<<NB_DN, 256, 0, stream>>>(
      h_r, h_s, counts, ebase, dn_off, wbd_e, wbd_s, oe, out);
  combine_kernel<<<T_TOK, 256, 0, stream>>>(tok_slot, tok_w, oe, out);
}